// Round 5
// baseline (299.450 us; speedup 1.0000x reference)
//
#include <hip/hip_runtime.h>
#include <stdint.h>

#define NROW    8192
#define CDIM    256
#define NCODE   16384
#define MARGINF 1.6e-4f

typedef short short8 __attribute__((ext_vector_type(8)));
typedef float floatx4 __attribute__((ext_vector_type(4)));
typedef _Float16 half2v __attribute__((ext_vector_type(2)));

__device__ inline ushort f2bf(float f) {
    unsigned u = __builtin_bit_cast(unsigned, f);
    unsigned r = (u + 0x7fffu + ((u >> 16) & 1u)) >> 16;
    return (ushort)r;
}
__device__ inline unsigned fsort(float v) {
    unsigned u = __builtin_bit_cast(unsigned, v);
    return (u >> 31) ? ~u : (u | 0x80000000u);
}

__device__ inline void gl_lds16(const ushort* g, ushort* lds) {
    __builtin_amdgcn_global_load_lds(
        (const __attribute__((address_space(1))) unsigned int*)(g),
        (__attribute__((address_space(3))) unsigned int*)(lds),
        16, 0, 0);
}

// ---------------------------------------------------------------------------
// x (B,C,H,W) fp32 -> xf32[n][c] and xbf[n][c] (bf16), n = b*1024 + hw
// ---------------------------------------------------------------------------
__global__ __launch_bounds__(256) void prep_x(const float* __restrict__ x,
                                              float* __restrict__ xf32,
                                              ushort* __restrict__ xbf) {
    __shared__ float tile[32][33];
    const int b = blockIdx.x, ht = blockIdx.y, ct = blockIdx.z;
    const int t = threadIdx.x;
    const int hw0 = ht * 32, c0 = ct * 32;
    {
        const int cc = t >> 5, hh = t & 31;
        #pragma unroll
        for (int i = 0; i < 4; ++i) {
            int cl = cc + i * 8;
            tile[cl][hh] = x[((size_t)(b * 256 + c0 + cl) << 10) + hw0 + hh];
        }
    }
    __syncthreads();
    {
        const int col = t & 31, row = t >> 5;
        #pragma unroll
        for (int i = 0; i < 4; ++i) {
            int r = row + i * 8;
            float v = tile[col][r];
            size_t o = ((size_t)(b * 1024 + hw0 + r) << 8) + c0 + col;
            xf32[o] = v;
            xbf[o] = f2bf(v);
        }
    }
}

// ---------------------------------------------------------------------------
// 2 threads per code j (one per 128-half): bf16 copy + exact np pairwise S2
// ---------------------------------------------------------------------------
__global__ __launch_bounds__(256) void prep_w2(const float* __restrict__ w,
                                               ushort* __restrict__ wbf,
                                               float* __restrict__ S2a) {
#pragma clang fp contract(off)
    const int gt = blockIdx.x * 256 + threadIdx.x;
    const int j = gt >> 1, h = gt & 1;
    const float* a = w + ((size_t)j << 8) + h * 128;
    ushort* orow = wbf + ((size_t)j << 8) + h * 128;
    float r8[8];
    #pragma unroll
    for (int l = 0; l < 8; ++l) { float v = a[l]; r8[l] = v * v; }
    for (int i = 8; i < 128; i += 8) {
        #pragma unroll
        for (int l = 0; l < 8; ++l) { float v = a[i + l]; r8[l] = r8[l] + v * v; }
    }
    float hs = ((r8[0] + r8[1]) + (r8[2] + r8[3])) + ((r8[4] + r8[5]) + (r8[6] + r8[7]));
    float other = __shfl_xor(hs, 1);
    if (h == 0) S2a[j] = hs + other;   // fl(hs0 + hs1) — np order
    for (int i = 0; i < 128; i += 8) {
        ushort u8[8];
        #pragma unroll
        for (int l = 0; l < 8; ++l) u8[l] = f2bf(a[i + l]);
        *(ushort4*)(orow + i)     = make_ushort4(u8[0], u8[1], u8[2], u8[3]);
        *(ushort4*)(orow + i + 4) = make_ushort4(u8[4], u8[5], u8[6], u8[7]);
    }
}

// ---------------------------------------------------------------------------
// bf16 MFMA GEMM with CODES on M, QUERIES on N (cheap in-lane epilogue).
// global_load_lds staging, XOR-swizzled LDS layout.
// Emits per (query row, 16-code block) min approx score as fp16:
//   bm16[n][1024], 16-block id jb = blockIdx.y*8 + wr*4 + mi.
// score = S2[j] - 2 * x.w  (S1 omitted: constant per row)
// ---------------------------------------------------------------------------
__global__ __launch_bounds__(256) void gemm_min(const ushort* __restrict__ Wb,
                                                const ushort* __restrict__ Xb,
                                                const float* __restrict__ S2a,
                                                ushort* __restrict__ bm16) {
    __shared__ __attribute__((aligned(16))) ushort As[8192];  // codes  [128][64] swz
    __shared__ __attribute__((aligned(16))) ushort Bs[8192];  // queries[128][64] swz
    __shared__ __attribute__((aligned(16))) ushort stg[128 * 8];

    const int n0 = blockIdx.x * 128;   // query block
    const int j0 = blockIdx.y * 128;   // code block
    const int t  = threadIdx.x;
    const int wv = t >> 6, l = t & 63;
    const int wr = wv >> 1, wc = wv & 1;   // wr: code 64-half, wc: query 64-half
    const int q  = l >> 4, c = l & 15;

    const int lr = l >> 3;
    const int lperm = (l & 7) ^ lr;
    const size_t gA0 = ((size_t)(j0 + wv * 32 + lr) << 8) + lperm * 8;
    const size_t gB0 = ((size_t)(n0 + wv * 32 + lr) << 8) + lperm * 8;
    const int ldsbase = wv * 2048;

    floatx4 acc[4][4];
    #pragma unroll
    for (int mi = 0; mi < 4; ++mi)
        #pragma unroll
        for (int ni = 0; ni < 4; ++ni)
            acc[mi][ni] = (floatx4){0.f, 0.f, 0.f, 0.f};

    for (int kb = 0; kb < 4; ++kb) {
        if (kb) __syncthreads();
        #pragma unroll
        for (int ca = 0; ca < 4; ++ca) {
            gl_lds16(Wb + gA0 + ca * 2048 + kb * 64, As + ldsbase + ca * 512);
            gl_lds16(Xb + gB0 + ca * 2048 + kb * 64, Bs + ldsbase + ca * 512);
        }
        __syncthreads();
        #pragma unroll
        for (int kk = 0; kk < 2; ++kk) {
            short8 af[4], bf[4];
            #pragma unroll
            for (int mi = 0; mi < 4; ++mi) {
                int row = wr * 64 + mi * 16 + c;
                int pos = (kk * 4 + q) ^ (c & 7);
                af[mi] = *(const short8*)&As[row * 64 + pos * 8];
            }
            #pragma unroll
            for (int ni = 0; ni < 4; ++ni) {
                int row = wc * 64 + ni * 16 + c;
                int pos = (kk * 4 + q) ^ (c & 7);
                bf[ni] = *(const short8*)&Bs[row * 64 + pos * 8];
            }
            #pragma unroll
            for (int mi = 0; mi < 4; ++mi)
                #pragma unroll
                for (int ni = 0; ni < 4; ++ni)
                    acc[mi][ni] = __builtin_amdgcn_mfma_f32_16x16x32_bf16(
                        af[mi], bf[ni], acc[mi][ni], 0, 0, 0);
        }
    }

    // Epilogue: D rows = codes (q*4+r), cols = queries (c).
    // Min over the 16 codes of block mi for query col c:
    //   in-lane min over r (4 regs), then shfl over q (lanes 16, 32 apart).
    #pragma unroll
    for (int mi = 0; mi < 4; ++mi) {
        float4 s2 = *(const float4*)&S2a[j0 + wr * 64 + mi * 16 + (q << 2)];
        #pragma unroll
        for (int ni = 0; ni < 4; ++ni) {
            float m0 = fmaf(-2.f, acc[mi][ni][0], s2.x);
            float m1 = fmaf(-2.f, acc[mi][ni][1], s2.y);
            float m2 = fmaf(-2.f, acc[mi][ni][2], s2.z);
            float m3 = fmaf(-2.f, acc[mi][ni][3], s2.w);
            float m = fminf(fminf(m0, m1), fminf(m2, m3));
            m = fminf(m, __shfl_xor(m, 16));
            m = fminf(m, __shfl_xor(m, 32));
            if (q == 0) {
                int qr = wc * 64 + ni * 16 + c;        // query row in block
                stg[qr * 8 + wr * 4 + mi] =
                    __builtin_bit_cast(ushort, (_Float16)m);
            }
        }
    }
    __syncthreads();
    if (t < 128) {
        uint4 v = *(const uint4*)&stg[t * 8];
        *(uint4*)(bm16 + ((size_t)(n0 + t) << 10) + blockIdx.y * 8) = v;
    }
}

// ---------------------------------------------------------------------------
// Per row: min over 1024 16-block mins (fp16), exactly rescore (np-fp32
// mirror) all codes of blocks within MARGIN; first-index ties. Then loss
// contribution for this row (loss pre-zeroed by memset).
// ---------------------------------------------------------------------------
__global__ __launch_bounds__(256) void rescore2(const unsigned* __restrict__ bm32,
                                                const float* __restrict__ xf32,
                                                const float* __restrict__ w,
                                                const float* __restrict__ S2a,
                                                int* __restrict__ idxb,
                                                float* __restrict__ xcode,
                                                float* __restrict__ loss) {
#pragma clang fp contract(off)
    __shared__ float xrow[256];
    __shared__ float red[256];
    __shared__ unsigned long long redk[256];
    __shared__ short list[1024];
    __shared__ int np_;
    __shared__ float sS1[2];
    const int n = blockIdx.x, t = threadIdx.x;
    if (t == 0) np_ = 0;
    xrow[t] = xf32[((size_t)n << 8) + t];
    const uint2 bm = *(const uint2*)(bm32 + ((size_t)n << 9) + t * 2);
    const half2v ha = __builtin_bit_cast(half2v, bm.x);
    const half2v hb = __builtin_bit_cast(half2v, bm.y);
    float v4[4] = {(float)ha[0], (float)ha[1], (float)hb[0], (float)hb[1]};
    float m = fminf(fminf(v4[0], v4[1]), fminf(v4[2], v4[3]));
    red[t] = m;
    __syncthreads();
    for (int s = 128; s > 0; s >>= 1) {
        if (t < s) red[t] = fminf(red[t], red[t + s]);
        __syncthreads();
    }
    const float thr = red[0] + MARGINF;
    #pragma unroll
    for (int i = 0; i < 4; ++i)
        if (v4[i] <= thr) { int p = atomicAdd(&np_, 1); list[p] = (short)(t * 4 + i); }
    if (t < 2) {   // exact np pairwise S1 halves
        const float* a = &xrow[t * 128];
        float r8[8];
        #pragma unroll
        for (int l = 0; l < 8; ++l) { float v = a[l]; r8[l] = v * v; }
        for (int i = 8; i < 128; i += 8) {
            #pragma unroll
            for (int l = 0; l < 8; ++l) { float v = a[i + l]; r8[l] = r8[l] + v * v; }
        }
        sS1[t] = ((r8[0] + r8[1]) + (r8[2] + r8[3])) + ((r8[4] + r8[5]) + (r8[6] + r8[7]));
    }
    __syncthreads();
    const int total = np_ * 16;
    const float S1n = sS1[0] + sS1[1];
    unsigned long long best = ~0ull;
    for (int it = t; it < total; it += 256) {
        const int j = (int)list[it >> 4] * 16 + (it & 15);
        const float* wr_ = w + ((size_t)j << 8);
        float g = 0.f;
        for (int k = 0; k < 256; k += 4) {   // sequential FMA in k-order (BLAS)
            float4 wv = *(const float4*)(wr_ + k);
            g = fmaf(xrow[k],     wv.x, g);
            g = fmaf(xrow[k + 1], wv.y, g);
            g = fmaf(xrow[k + 2], wv.z, g);
            g = fmaf(xrow[k + 3], wv.w, g);
        }
        float d = (S1n + S2a[j]) - 2.0f * g;
        unsigned long long key = ((unsigned long long)fsort(d) << 32) | (unsigned)j;
        if (key < best) best = key;
    }
    redk[t] = best;
    __syncthreads();
    for (int s = 128; s > 0; s >>= 1) {
        if (t < s) { if (redk[t + s] < redk[t]) redk[t] = redk[t + s]; }
        __syncthreads();
    }
    const int J = (int)(redk[0] & 0xffffffffu);
    if (t == 0) {
        idxb[n] = J;
        xcode[n] = (float)J;
    }
    // loss contribution for this row
    float dv = w[((size_t)J << 8) + t] - xrow[t];
    float lacc = dv * dv;
    #pragma unroll
    for (int off = 32; off; off >>= 1) lacc += __shfl_xor(lacc, off);
    if ((t & 63) == 0) red[t >> 6] = lacc;
    __syncthreads();
    if (t == 0) {
        float p = (red[0] + red[1]) + (red[2] + red[3]);
        atomicAdd(loss, p * (1.25f / 2097152.0f));
    }
}

// ---------------------------------------------------------------------------
// xq_img gather (loss handled in rescore2)
// ---------------------------------------------------------------------------
__global__ __launch_bounds__(256) void outputs_k(const float* __restrict__ w,
                                                 const int* __restrict__ idxb,
                                                 float* __restrict__ out) {
    const int b = blockIdx.x, hq = blockIdx.y, cs = blockIdx.z;
    const int t = threadIdx.x;
    const int hw = hq * 256 + t;
    const int n = (b << 10) + hw;
    const int id = idxb[n];
    #pragma unroll 4
    for (int ci = 0; ci < 32; ++ci) {
        const int c_ = cs * 32 + ci;
        const size_t oo = ((size_t)((b << 8) + c_) << 10) + hw;
        out[oo] = w[((size_t)id << 8) + c_];
    }
}

// ---------------------------------------------------------------------------
extern "C" void kernel_launch(void* const* d_in, const int* in_sizes, int n_in,
                              void* d_out, int out_size, void* d_ws, size_t ws_size,
                              hipStream_t stream) {
    const float* x = (const float*)d_in[0];
    const float* w = (const float*)d_in[1];
    float* out = (float*)d_out;

    char* ws = (char*)d_ws;
    const size_t MB = 1024u * 1024u;
    ushort* xbf   = (ushort*)(ws);                   //  4 MiB
    float*  xf32  = (float*) (ws + 4 * MB);          //  8 MiB
    ushort* wbf   = (ushort*)(ws + 12 * MB);         //  8 MiB
    float*  S2a   = (float*) (ws + 20 * MB);         // 64 KiB
    ushort* bm16  = (ushort*)(ws + 21 * MB);         // 16 MiB
    int*    idxb  = (int*)   (ws + 37 * MB);         // 32 KiB

    float* loss_ptr  = out + 2097152;
    float* xcode_ptr = out + 2097153;

    hipMemsetAsync((void*)loss_ptr, 0, 4, stream);

    prep_x  <<<dim3(8, 32, 8), 256, 0, stream>>>(x, xf32, xbf);
    prep_w2 <<<dim3(128),      256, 0, stream>>>(w, wbf, S2a);
    gemm_min<<<dim3(64, 128),  256, 0, stream>>>(wbf, xbf, S2a, bm16);
    rescore2<<<dim3(8192),     256, 0, stream>>>((const unsigned*)bm16, xf32, w,
                                                 S2a, idxb, xcode_ptr, loss_ptr);
    outputs_k<<<dim3(8, 4, 8), 256, 0, stream>>>(w, idxb, out);
}

// Round 6
// 295.530 us; speedup vs baseline: 1.0133x; 1.0133x over previous
//
#include <hip/hip_runtime.h>
#include <stdint.h>

#define NROW    8192
#define CDIM    256
#define NCODE   16384
#define MARGINF 1.6e-4f

typedef short short8 __attribute__((ext_vector_type(8)));
typedef float floatx4 __attribute__((ext_vector_type(4)));
typedef _Float16 half2v __attribute__((ext_vector_type(2)));

__device__ inline ushort f2bf(float f) {
    unsigned u = __builtin_bit_cast(unsigned, f);
    unsigned r = (u + 0x7fffu + ((u >> 16) & 1u)) >> 16;
    return (ushort)r;
}
__device__ inline unsigned fsort(float v) {
    unsigned u = __builtin_bit_cast(unsigned, v);
    return (u >> 31) ? ~u : (u | 0x80000000u);
}

__device__ inline void gl_lds16(const ushort* g, ushort* lds) {
    __builtin_amdgcn_global_load_lds(
        (const __attribute__((address_space(1))) unsigned int*)(g),
        (__attribute__((address_space(3))) unsigned int*)(lds),
        16, 0, 0);
}

// ---------------------------------------------------------------------------
// x (B,C,H,W) fp32 -> xf32[n][c] and xbf[n][c] (bf16), n = b*1024 + hw
// ---------------------------------------------------------------------------
__global__ __launch_bounds__(256) void prep_x(const float* __restrict__ x,
                                              float* __restrict__ xf32,
                                              ushort* __restrict__ xbf) {
    __shared__ float tile[32][33];
    const int b = blockIdx.x, ht = blockIdx.y, ct = blockIdx.z;
    const int t = threadIdx.x;
    const int hw0 = ht * 32, c0 = ct * 32;
    {
        const int cc = t >> 5, hh = t & 31;
        #pragma unroll
        for (int i = 0; i < 4; ++i) {
            int cl = cc + i * 8;
            tile[cl][hh] = x[((size_t)(b * 256 + c0 + cl) << 10) + hw0 + hh];
        }
    }
    __syncthreads();
    {
        const int col = t & 31, row = t >> 5;
        #pragma unroll
        for (int i = 0; i < 4; ++i) {
            int r = row + i * 8;
            float v = tile[col][r];
            size_t o = ((size_t)(b * 1024 + hw0 + r) << 8) + c0 + col;
            xf32[o] = v;
            xbf[o] = f2bf(v);
        }
    }
}

// ---------------------------------------------------------------------------
// 2 threads per code j (one per 128-half): bf16 copy + exact np pairwise S2
// ---------------------------------------------------------------------------
__global__ __launch_bounds__(256) void prep_w2(const float* __restrict__ w,
                                               ushort* __restrict__ wbf,
                                               float* __restrict__ S2a) {
#pragma clang fp contract(off)
    const int gt = blockIdx.x * 256 + threadIdx.x;
    const int j = gt >> 1, h = gt & 1;
    const float* a = w + ((size_t)j << 8) + h * 128;
    ushort* orow = wbf + ((size_t)j << 8) + h * 128;
    float r8[8];
    #pragma unroll
    for (int l = 0; l < 8; ++l) { float v = a[l]; r8[l] = v * v; }
    for (int i = 8; i < 128; i += 8) {
        #pragma unroll
        for (int l = 0; l < 8; ++l) { float v = a[i + l]; r8[l] = r8[l] + v * v; }
    }
    float hs = ((r8[0] + r8[1]) + (r8[2] + r8[3])) + ((r8[4] + r8[5]) + (r8[6] + r8[7]));
    float other = __shfl_xor(hs, 1);
    if (h == 0) S2a[j] = hs + other;   // fl(hs0 + hs1) — np order
    for (int i = 0; i < 128; i += 8) {
        ushort u8[8];
        #pragma unroll
        for (int l = 0; l < 8; ++l) u8[l] = f2bf(a[i + l]);
        *(ushort4*)(orow + i)     = make_ushort4(u8[0], u8[1], u8[2], u8[3]);
        *(ushort4*)(orow + i + 4) = make_ushort4(u8[4], u8[5], u8[6], u8[7]);
    }
}

// ---------------------------------------------------------------------------
// bf16 MFMA GEMM with CODES on M, QUERIES on N (cheap in-lane epilogue).
// global_load_lds staging, XOR-swizzled LDS layout.
// Emits per (query row, 16-code block) min approx score as fp16:
//   bm16[n][1024], 16-block id jb = blockIdx.y*8 + wr*4 + mi.
// score = S2[j] - 2 * x.w  (S1 omitted: constant per row)
// ---------------------------------------------------------------------------
__global__ __launch_bounds__(256) void gemm_min(const ushort* __restrict__ Wb,
                                                const ushort* __restrict__ Xb,
                                                const float* __restrict__ S2a,
                                                ushort* __restrict__ bm16) {
    __shared__ __attribute__((aligned(16))) ushort As[8192];  // codes  [128][64] swz
    __shared__ __attribute__((aligned(16))) ushort Bs[8192];  // queries[128][64] swz
    __shared__ __attribute__((aligned(16))) ushort stg[128 * 8];

    const int n0 = blockIdx.x * 128;   // query block
    const int j0 = blockIdx.y * 128;   // code block
    const int t  = threadIdx.x;
    const int wv = t >> 6, l = t & 63;
    const int wr = wv >> 1, wc = wv & 1;   // wr: code 64-half, wc: query 64-half
    const int q  = l >> 4, c = l & 15;

    const int lr = l >> 3;
    const int lperm = (l & 7) ^ lr;
    const size_t gA0 = ((size_t)(j0 + wv * 32 + lr) << 8) + lperm * 8;
    const size_t gB0 = ((size_t)(n0 + wv * 32 + lr) << 8) + lperm * 8;
    const int ldsbase = wv * 2048;

    floatx4 acc[4][4];
    #pragma unroll
    for (int mi = 0; mi < 4; ++mi)
        #pragma unroll
        for (int ni = 0; ni < 4; ++ni)
            acc[mi][ni] = (floatx4){0.f, 0.f, 0.f, 0.f};

    for (int kb = 0; kb < 4; ++kb) {
        if (kb) __syncthreads();
        #pragma unroll
        for (int ca = 0; ca < 4; ++ca) {
            gl_lds16(Wb + gA0 + ca * 2048 + kb * 64, As + ldsbase + ca * 512);
            gl_lds16(Xb + gB0 + ca * 2048 + kb * 64, Bs + ldsbase + ca * 512);
        }
        __syncthreads();
        #pragma unroll
        for (int kk = 0; kk < 2; ++kk) {
            short8 af[4], bf[4];
            #pragma unroll
            for (int mi = 0; mi < 4; ++mi) {
                int row = wr * 64 + mi * 16 + c;
                int pos = (kk * 4 + q) ^ (c & 7);
                af[mi] = *(const short8*)&As[row * 64 + pos * 8];
            }
            #pragma unroll
            for (int ni = 0; ni < 4; ++ni) {
                int row = wc * 64 + ni * 16 + c;
                int pos = (kk * 4 + q) ^ (c & 7);
                bf[ni] = *(const short8*)&Bs[row * 64 + pos * 8];
            }
            #pragma unroll
            for (int mi = 0; mi < 4; ++mi)
                #pragma unroll
                for (int ni = 0; ni < 4; ++ni)
                    acc[mi][ni] = __builtin_amdgcn_mfma_f32_16x16x32_bf16(
                        af[mi], bf[ni], acc[mi][ni], 0, 0, 0);
        }
    }

    // Epilogue: D rows = codes (q*4+r), cols = queries (c).
    #pragma unroll
    for (int mi = 0; mi < 4; ++mi) {
        float4 s2 = *(const float4*)&S2a[j0 + wr * 64 + mi * 16 + (q << 2)];
        #pragma unroll
        for (int ni = 0; ni < 4; ++ni) {
            float m0 = fmaf(-2.f, acc[mi][ni][0], s2.x);
            float m1 = fmaf(-2.f, acc[mi][ni][1], s2.y);
            float m2 = fmaf(-2.f, acc[mi][ni][2], s2.z);
            float m3 = fmaf(-2.f, acc[mi][ni][3], s2.w);
            float m = fminf(fminf(m0, m1), fminf(m2, m3));
            m = fminf(m, __shfl_xor(m, 16));
            m = fminf(m, __shfl_xor(m, 32));
            if (q == 0) {
                int qr = wc * 64 + ni * 16 + c;        // query row in block
                stg[qr * 8 + wr * 4 + mi] =
                    __builtin_bit_cast(ushort, (_Float16)m);
            }
        }
    }
    __syncthreads();
    if (t < 128) {
        uint4 v = *(const uint4*)&stg[t * 8];
        *(uint4*)(bm16 + ((size_t)(n0 + t) << 10) + blockIdx.y * 8) = v;
    }
}

// ---------------------------------------------------------------------------
// Per row: min over 1024 16-block mins (fp16); candidate blocks within MARGIN
// get their 16 codes' w-rows cooperatively prefetched into LDS, then exact
// np-fp32 rescore (sequential k-order FMA) from LDS; first-index tie-break.
// Loss contribution fused (loss pre-zeroed by memset).
// ---------------------------------------------------------------------------
__global__ __launch_bounds__(256) void rescore3(const ushort* __restrict__ bm16,
                                                const float* __restrict__ xf32,
                                                const float* __restrict__ w,
                                                const float* __restrict__ S2a,
                                                int* __restrict__ idxb,
                                                float* __restrict__ xcode,
                                                float* __restrict__ loss) {
#pragma clang fp contract(off)
    __shared__ float xrow[256];
    __shared__ float wpart[4];
    __shared__ unsigned long long kpart[4];
    __shared__ short list[1024];
    __shared__ int np_;
    __shared__ float sS1[2];
    __shared__ float wtile[2 * 16 * 260];   // 2 blocks x 16 rows x (256+4 pad)

    const int n = blockIdx.x, t = threadIdx.x;
    const int wv = t >> 6, l = t & 63;
    if (t == 0) np_ = 0;
    xrow[t] = xf32[((size_t)n << 8) + t];
    const ushort4 bmv = *(const ushort4*)(bm16 + ((size_t)n << 10) + t * 4);
    float v4[4] = {(float)__builtin_bit_cast(_Float16, bmv.x),
                   (float)__builtin_bit_cast(_Float16, bmv.y),
                   (float)__builtin_bit_cast(_Float16, bmv.z),
                   (float)__builtin_bit_cast(_Float16, bmv.w)};
    float m = fminf(fminf(v4[0], v4[1]), fminf(v4[2], v4[3]));
    #pragma unroll
    for (int off = 1; off <= 32; off <<= 1) m = fminf(m, __shfl_xor(m, off));
    if (l == 0) wpart[wv] = m;
    __syncthreads();
    const float thr = fminf(fminf(wpart[0], wpart[1]),
                            fminf(wpart[2], wpart[3])) + MARGINF;
    #pragma unroll
    for (int i = 0; i < 4; ++i)
        if (v4[i] <= thr) { int p = atomicAdd(&np_, 1); list[p] = (short)(t * 4 + i); }
    if (t < 2) {   // exact np pairwise S1 halves
        const float* a = &xrow[t * 128];
        float r8[8];
        #pragma unroll
        for (int lo = 0; lo < 8; ++lo) { float v = a[lo]; r8[lo] = v * v; }
        for (int i = 8; i < 128; i += 8) {
            #pragma unroll
            for (int lo = 0; lo < 8; ++lo) { float v = a[i + lo]; r8[lo] = r8[lo] + v * v; }
        }
        sS1[t] = ((r8[0] + r8[1]) + (r8[2] + r8[3])) + ((r8[4] + r8[5]) + (r8[6] + r8[7]));
    }
    __syncthreads();

    const float S1n = sS1[0] + sS1[1];
    const int nblk = np_;
    unsigned long long best = ~0ull;
    for (int c0 = 0; c0 < nblk; c0 += 2) {
        const int nb = (nblk - c0) < 2 ? (nblk - c0) : 2;
        // cooperative prefetch: nb*16 rows x 256 f32, coalesced float4
        for (int r = 0; r < nb * 4; ++r) {
            int flat = r * 1024 + t * 4;
            int row = flat >> 8;
            int k = flat & 255;
            int j = (int)list[c0 + (row >> 4)] * 16 + (row & 15);
            *(float4*)&wtile[row * 260 + k] = *(const float4*)&w[((size_t)j << 8) + k];
        }
        __syncthreads();
        if (t < nb * 16) {
            const int j = (int)list[c0 + (t >> 4)] * 16 + (t & 15);
            const float* wr_ = &wtile[t * 260];
            float g = 0.f;
            for (int k = 0; k < 256; k += 4) {   // sequential FMA in k-order (BLAS)
                float4 wvv = *(const float4*)(wr_ + k);
                g = fmaf(xrow[k],     wvv.x, g);
                g = fmaf(xrow[k + 1], wvv.y, g);
                g = fmaf(xrow[k + 2], wvv.z, g);
                g = fmaf(xrow[k + 3], wvv.w, g);
            }
            float d = (S1n + S2a[j]) - 2.0f * g;
            unsigned long long key = ((unsigned long long)fsort(d) << 32) | (unsigned)j;
            if (key < best) best = key;
        }
        __syncthreads();
    }

    #pragma unroll
    for (int off = 1; off <= 32; off <<= 1) {
        unsigned long long o = __shfl_xor(best, off);
        if (o < best) best = o;
    }
    if (l == 0) kpart[wv] = best;
    __syncthreads();
    unsigned long long k01 = kpart[0] < kpart[1] ? kpart[0] : kpart[1];
    unsigned long long k23 = kpart[2] < kpart[3] ? kpart[2] : kpart[3];
    const int J = (int)((k01 < k23 ? k01 : k23) & 0xffffffffu);
    if (t == 0) {
        idxb[n] = J;
        xcode[n] = (float)J;
    }
    // loss contribution for this row (w[J] row is L2-hot from the dots)
    float dv = w[((size_t)J << 8) + t] - xrow[t];
    float lacc = dv * dv;
    #pragma unroll
    for (int off = 1; off <= 32; off <<= 1) lacc += __shfl_xor(lacc, off);
    if (l == 0) wpart[wv] = lacc;
    __syncthreads();
    if (t == 0) {
        float p = (wpart[0] + wpart[1]) + (wpart[2] + wpart[3]);
        atomicAdd(loss, p * (1.25f / 2097152.0f));
    }
}

// ---------------------------------------------------------------------------
// xq_img gather (loss handled in rescore3)
// ---------------------------------------------------------------------------
__global__ __launch_bounds__(256) void outputs_k(const float* __restrict__ w,
                                                 const int* __restrict__ idxb,
                                                 float* __restrict__ out) {
    const int b = blockIdx.x, hq = blockIdx.y, cs = blockIdx.z;
    const int t = threadIdx.x;
    const int hw = hq * 256 + t;
    const int n = (b << 10) + hw;
    const int id = idxb[n];
    #pragma unroll 4
    for (int ci = 0; ci < 32; ++ci) {
        const int c_ = cs * 32 + ci;
        const size_t oo = ((size_t)((b << 8) + c_) << 10) + hw;
        out[oo] = w[((size_t)id << 8) + c_];
    }
}

// ---------------------------------------------------------------------------
extern "C" void kernel_launch(void* const* d_in, const int* in_sizes, int n_in,
                              void* d_out, int out_size, void* d_ws, size_t ws_size,
                              hipStream_t stream) {
    const float* x = (const float*)d_in[0];
    const float* w = (const float*)d_in[1];
    float* out = (float*)d_out;

    char* ws = (char*)d_ws;
    const size_t MB = 1024u * 1024u;
    ushort* xbf   = (ushort*)(ws);                   //  4 MiB
    float*  xf32  = (float*) (ws + 4 * MB);          //  8 MiB
    ushort* wbf   = (ushort*)(ws + 12 * MB);         //  8 MiB
    float*  S2a   = (float*) (ws + 20 * MB);         // 64 KiB
    ushort* bm16  = (ushort*)(ws + 21 * MB);         // 16 MiB
    int*    idxb  = (int*)   (ws + 37 * MB);         // 32 KiB

    float* loss_ptr  = out + 2097152;
    float* xcode_ptr = out + 2097153;

    hipMemsetAsync((void*)loss_ptr, 0, 4, stream);

    prep_x  <<<dim3(8, 32, 8), 256, 0, stream>>>(x, xf32, xbf);
    prep_w2 <<<dim3(128),      256, 0, stream>>>(w, wbf, S2a);
    gemm_min<<<dim3(64, 128),  256, 0, stream>>>(wbf, xbf, S2a, bm16);
    rescore3<<<dim3(8192),     256, 0, stream>>>(bm16, xf32, w, S2a, idxb,
                                                 xcode_ptr, loss_ptr);
    outputs_k<<<dim3(8, 4, 8), 256, 0, stream>>>(w, idxb, out);
}